// Round 2
// baseline (34139.725 us; speedup 1.0000x reference)
//
#include <hip/hip_runtime.h>
#include <hip/hip_bf16.h>
#include <cstdint>

#define TE   16
#define NTHR 256

// GRU over L=4 metapath positions. D=64, HD=512, gates (r,z,n) -> 1536 rows.
// Block = 16 edges, 256 threads. Thread (jj=tid&63, eg=tid>>6) computes
// outputs j = t0+jj for edges e = eg*4 .. eg*4+3 of each 64-wide j-tile.
__global__ __launch_bounds__(NTHR) void gru_kernel(
    const float* __restrict__ feat,
    const int*   __restrict__ emi,
    const float* __restrict__ w_ih,
    const float* __restrict__ w_hh,
    const float* __restrict__ b_ih,
    const float* __restrict__ b_hh,
    float* __restrict__ eft,
    int E)
{
    __shared__ float hs[TE][520];   // h state, pad 520 (pads keep b128s clean)
    __shared__ float xs[TE][68];    // gathered features for current step
    __shared__ float wt[64][68];    // staged 64x64 weight tile (pad 68 -> conflict-free b128 reads)

    const int tid = threadIdx.x;
    const int jj  = tid & 63;
    const int eg  = tid >> 6;
    const int e0  = blockIdx.x * TE;

    for (int i = tid; i < TE * 520; i += NTHR) (&hs[0][0])[i] = 0.f;
    __syncthreads();

    for (int l = 0; l < 4; ++l) {
        // ---- gather x for this step: 16 rows x 64 floats ----
        {
            int row  = tid >> 4;
            int seg  = (tid & 15) << 2;
            int e    = e0 + row;
            int nidx = (e < E) ? emi[e * 4 + l] : 0;
            *(float4*)&xs[row][seg] = *(const float4*)&feat[(size_t)nidx * 64 + seg];
        }
        __syncthreads();

        for (int tt = 0; tt < 8; ++tt) {
            const int t0 = tt << 6;
            float ar[4]  = {0.f, 0.f, 0.f, 0.f};
            float az[4]  = {0.f, 0.f, 0.f, 0.f};
            float ani[4] = {0.f, 0.f, 0.f, 0.f};
            float anh[4] = {0.f, 0.f, 0.f, 0.f};

            // ---- input contributions: gi = x . w_ih[g*512 + t0 + jj]  (K=64) ----
            #pragma unroll
            for (int g = 0; g < 3; ++g) {
                {   // stage w_ih rows [g*512+t0 .. +63], k=0..63 (coalesced float4)
                    int r  = tid >> 2;
                    int kb = (tid & 3) << 4;
                    const float* src = &w_ih[(size_t)(g * 512 + t0 + r) * 64 + kb];
                    #pragma unroll
                    for (int q = 0; q < 4; ++q)
                        *(float4*)&wt[r][kb + (q << 2)] = *(const float4*)(src + (q << 2));
                }
                __syncthreads();
                float* acc = (g == 0) ? ar : (g == 1) ? az : ani;
                #pragma unroll
                for (int k4 = 0; k4 < 16; ++k4) {
                    float4 wv = *(const float4*)&wt[jj][k4 << 2];
                    #pragma unroll
                    for (int e4 = 0; e4 < 4; ++e4) {
                        float4 hv = *(const float4*)&xs[(eg << 2) + e4][k4 << 2];
                        acc[e4] += hv.x * wv.x + hv.y * wv.y + hv.z * wv.z + hv.w * wv.w;
                    }
                }
                __syncthreads();
            }

            // ---- hidden contributions: gh = h . w_hh[g*512 + t0 + jj]  (K=512) ----
            // Skip at l==0: h is identically zero (saves 25% of the GEMM work).
            if (l > 0) {
                #pragma unroll
                for (int g = 0; g < 3; ++g) {
                    float* acc = (g == 0) ? ar : (g == 1) ? az : anh;
                    for (int kc = 0; kc < 8; ++kc) {
                        {
                            int r  = tid >> 2;
                            int kb = (tid & 3) << 4;
                            const float* src = &w_hh[(size_t)(g * 512 + t0 + r) * 512 + (kc << 6) + kb];
                            #pragma unroll
                            for (int q = 0; q < 4; ++q)
                                *(float4*)&wt[r][kb + (q << 2)] = *(const float4*)(src + (q << 2));
                        }
                        __syncthreads();
                        #pragma unroll
                        for (int k4 = 0; k4 < 16; ++k4) {
                            float4 wv = *(const float4*)&wt[jj][k4 << 2];
                            #pragma unroll
                            for (int e4 = 0; e4 < 4; ++e4) {
                                float4 hv = *(const float4*)&hs[(eg << 2) + e4][(kc << 6) + (k4 << 2)];
                                acc[e4] += hv.x * wv.x + hv.y * wv.y + hv.z * wv.z + hv.w * wv.w;
                            }
                        }
                        __syncthreads();
                    }
                }
            }

            // ---- gate combine; h_new goes to eft (global) to dodge LDS dbuf ----
            const int j = t0 + jj;
            const float bir = b_ih[j],        bhr = b_hh[j];
            const float biz = b_ih[512 + j],  bhz = b_hh[512 + j];
            const float bin = b_ih[1024 + j], bhn = b_hh[1024 + j];
            #pragma unroll
            for (int e4 = 0; e4 < 4; ++e4) {
                const int e = (eg << 2) + e4;
                float r  = 1.f / (1.f + __expf(-(ar[e4] + bir + bhr)));
                float z  = 1.f / (1.f + __expf(-(az[e4] + biz + bhz)));
                float n  = tanhf(ani[e4] + bin + r * (anh[e4] + bhn));
                float hn2 = (1.f - z) * n + z * hs[e][j];
                if (e0 + e < E) eft[(size_t)(e0 + e) * 512 + j] = hn2;
            }
        }

        // ---- reload h state from eft (same thread wrote these addresses; volatile
        //      bypasses L1 so we read the post-store L2 data) ----
        if (l < 3) {
            __syncthreads();
            const volatile float* veft = eft;
            for (int tt = 0; tt < 8; ++tt) {
                #pragma unroll
                for (int e4 = 0; e4 < 4; ++e4) {
                    const int e = (eg << 2) + e4;
                    float v = (e0 + e < E) ? veft[(size_t)(e0 + e) * 512 + (tt << 6) + jj] : 0.f;
                    hs[e][(tt << 6) + jj] = v;
                }
            }
            __syncthreads();
        }
    }
}

// Per-(edge, head) attention logit -> exp (no max-subtraction: logits are O(1),
// softmax ratio is identical) -> denom accumulation per destination node.
__global__ __launch_bounds__(256) void attn_kernel(
    const float* __restrict__ eft, const float* __restrict__ attn,
    const int* __restrict__ dst, float* __restrict__ aexp,
    float* __restrict__ denom, int E)
{
    int g = blockIdx.x * 256 + threadIdx.x;
    if (g >= E * 8) return;
    int e = g >> 3, h = g & 7;
    const float* fp = &eft[(size_t)e * 512 + (h << 6)];
    const float* ap = &attn[h << 6];
    float a = 0.f;
    #pragma unroll
    for (int k = 0; k < 16; ++k) {
        float4 f = *(const float4*)(fp + (k << 2));
        float4 w = *(const float4*)(ap + (k << 2));
        a += f.x * w.x + f.y * w.y + f.z * w.z + f.w * w.w;
    }
    a = (a > 0.f) ? a : 0.001f * a;   // leaky relu, slope 0.001
    float ae = __expf(a);
    aexp[g] = ae;
    atomicAdd(&denom[(size_t)dst[e] * 8 + h], ae);
}

// Weighted scatter: out[dst[e], h, d] += eft[e,h,d] * aexp[e,h]/denom[dst[e],h]
__global__ __launch_bounds__(256) void scatter_kernel(
    const float* __restrict__ eft, const float* __restrict__ aexp,
    const float* __restrict__ denom, const int* __restrict__ dst,
    float* __restrict__ out, long long total)
{
    long long g = (long long)blockIdx.x * 256 + threadIdx.x;
    if (g >= total) return;
    int e = (int)(g >> 9);
    int j = (int)(g & 511);
    int h = j >> 6;
    int n = dst[e];
    float w = aexp[(size_t)e * 8 + h] / fmaxf(denom[(size_t)n * 8 + h], 1e-12f);
    atomicAdd(&out[(size_t)n * 512 + j], eft[g] * w);
}

extern "C" void kernel_launch(void* const* d_in, const int* in_sizes, int n_in,
                              void* d_out, int out_size, void* d_ws, size_t ws_size,
                              hipStream_t stream)
{
    const float* feat = (const float*)d_in[0];
    const int*   emi  = (const int*)d_in[1];
    const int*   dst  = (const int*)d_in[2];
    // d_in[3] = num_nodes scalar (derived from out_size instead)
    const float* w_ih = (const float*)d_in[4];
    const float* w_hh = (const float*)d_in[5];
    const float* b_ih = (const float*)d_in[6];
    const float* b_hh = (const float*)d_in[7];
    const float* attn = (const float*)d_in[8];

    const int E = in_sizes[1] / 4;      // edge_metapath_indices is [E, 4]
    const int N = out_size / 512;       // out is [N, 8, 64]

    float* eft   = (float*)d_ws;                  // E*512 floats (204.8 MB)
    float* aexp  = eft + (size_t)E * 512;         // E*8 floats
    float* denom = aexp + (size_t)E * 8;          // N*8 floats
    float* out   = (float*)d_out;

    (void)hipMemsetAsync(d_out, 0, (size_t)out_size * sizeof(float), stream);
    (void)hipMemsetAsync(denom, 0, (size_t)N * 8 * sizeof(float), stream);

    gru_kernel<<<(E + TE - 1) / TE, NTHR, 0, stream>>>(feat, emi, w_ih, w_hh, b_ih, b_hh, eft, E);
    attn_kernel<<<(E * 8 + 255) / 256, 256, 0, stream>>>(eft, attn, dst, aexp, denom, E);

    long long total = (long long)E * 512;
    scatter_kernel<<<(int)((total + 255) / 256), 256, 0, stream>>>(eft, aexp, denom, dst, out, total);
}

// Round 3
// 1973.951 us; speedup vs baseline: 17.2951x; 17.2951x over previous
//
#include <hip/hip_runtime.h>
#include <cstdint>

typedef __attribute__((ext_vector_type(8))) short          bf16x8;
typedef __attribute__((ext_vector_type(8))) unsigned short u16x8;
typedef __attribute__((ext_vector_type(4))) float          f32x4;

__device__ __forceinline__ unsigned short f2bf(float x) {
    union { float f; unsigned u; } v; v.f = x;
    unsigned r = v.u + 0x7FFF + ((v.u >> 16) & 1);   // RNE
    return (unsigned short)(r >> 16);
}
__device__ __forceinline__ float bf2f(unsigned short b) {
    union { float f; unsigned u; } v; v.u = ((unsigned)b) << 16;
    return v.f;
}

#define EB 64   // edges per block

// ---------------------------------------------------------------------------
// One-time converts: feat -> bf16 row-major; w_ih/w_hh -> bf16 in MFMA
// B-fragment-linear order: wb[(jt_glob*KB + kb)*64 + lane][i] holds
// W[jt_glob*16 + (lane&15)][kb*32 + (lane>>4)*8 + i].
// ---------------------------------------------------------------------------
__global__ __launch_bounds__(256) void conv_kernel(
    const float* __restrict__ feat, const float* __restrict__ w_ih,
    const float* __restrict__ w_hh,
    unsigned short* __restrict__ featb, unsigned short* __restrict__ wbi,
    unsigned short* __restrict__ wbh, int nfeat8)
{
    int t = blockIdx.x * 256 + threadIdx.x;
    if (t < nfeat8) {                       // features: 8 elems/thread
        u16x8 o;
        #pragma unroll
        for (int i = 0; i < 8; ++i) o[i] = f2bf(feat[(size_t)t * 8 + i]);
        *(u16x8*)&featb[(size_t)t * 8] = o;
    } else if (t < nfeat8 + 98304) {        // w_hh: 96 jt x 16 kb x 64 lanes
        int tt = t - nfeat8;
        int lane = tt & 63, q = tt >> 6;
        int jt = q >> 4, kb = q & 15;
        int j = jt * 16 + (lane & 15);
        int k0 = kb * 32 + (lane >> 4) * 8;
        u16x8 o;
        #pragma unroll
        for (int i = 0; i < 8; ++i) o[i] = f2bf(w_hh[(size_t)j * 512 + k0 + i]);
        *(u16x8*)&wbh[(size_t)tt * 8] = o;
    } else if (t < nfeat8 + 98304 + 12288) { // w_ih: 96 jt x 2 kb x 64 lanes
        int uu = t - nfeat8 - 98304;
        int lane = uu & 63, q = uu >> 6;
        int jt = q >> 1, kb = q & 1;
        int j = jt * 16 + (lane & 15);
        int k0 = kb * 32 + (lane >> 4) * 8;
        u16x8 o;
        #pragma unroll
        for (int i = 0; i < 8; ++i) o[i] = f2bf(w_ih[(size_t)j * 64 + k0 + i]);
        *(u16x8*)&wbi[(size_t)uu * 8] = o;
    }
}

// ---------------------------------------------------------------------------
// GRU via mfma_f32_16x16x32_bf16. Block = 64 edges, 4 waves; wave w owns
// j in [w*128, w*128+128) for ALL 64 edges (weights partitioned per wave).
// A-frag: row=lane&15, k=(lane>>4)*8+i.  B-frag: col=lane&15, same k.
// D: col=lane&15, row=(lane>>4)*4+reg.
// H state: bf16 in LDS, double-buffered, XOR-swizzled (idx ^ ((row&7)<<3)).
// ---------------------------------------------------------------------------
__global__ __launch_bounds__(256, 1) void gru_mfma_kernel(
    const unsigned short* __restrict__ featb,
    const int* __restrict__ emi,
    const unsigned short* __restrict__ wbi,
    const unsigned short* __restrict__ wbh,
    const float* __restrict__ b_ih,
    const float* __restrict__ b_hh,
    float* __restrict__ eft,
    int E)
{
    __shared__ unsigned short hb[2][64 * 512];  // 128 KB
    __shared__ unsigned short xb[64 * 64];      // 8 KB

    const int tid  = threadIdx.x;
    const int lane = tid & 63;
    const int w    = tid >> 6;
    const int g    = lane >> 4;
    const int c    = lane & 15;
    const int e0   = blockIdx.x * EB;
    const f32x4 fzero = {0.f, 0.f, 0.f, 0.f};

    for (int l = 0; l < 4; ++l) {
        const int rbuf = l & 1, wbuf = rbuf ^ 1;
        // ---- stage x (bf16) into swizzled LDS: 4 threads/row x 32B ----
        {
            int r = tid >> 2, p = tid & 3;
            int nidx = (e0 + r < E) ? emi[(e0 + r) * 4 + l] : 0;
            const unsigned short* src = featb + (size_t)nidx * 64 + p * 16;
            u16x8 v0 = *(const u16x8*)(src);
            u16x8 v1 = *(const u16x8*)(src + 8);
            int sw = (r & 7) << 3;
            *(u16x8*)&xb[r * 64 + ((p * 16 + 0) ^ sw)] = v0;
            *(u16x8*)&xb[r * 64 + ((p * 16 + 8) ^ sw)] = v1;
        }
        __syncthreads();

        for (int cc = 0; cc < 8; ++cc) {
            const int j0 = w * 128 + cc * 16;
            const int jt = j0 >> 4;           // 0..31 within a gate block
            f32x4 ar[4], az[4], ain[4], ahn[4];
            #pragma unroll
            for (int m = 0; m < 4; ++m) { ar[m] = fzero; az[m] = fzero; ain[m] = fzero; ahn[m] = fzero; }

            // ---- gi = x . W_ih^T  (K=64) ----
            #pragma unroll
            for (int kb = 0; kb < 2; ++kb) {
                bf16x8 br = *(const bf16x8*)(wbi + (((size_t)((jt     ) * 2 + kb)) * 64 + lane) * 8);
                bf16x8 bz = *(const bf16x8*)(wbi + (((size_t)((32 + jt) * 2 + kb)) * 64 + lane) * 8);
                bf16x8 bn = *(const bf16x8*)(wbi + (((size_t)((64 + jt) * 2 + kb)) * 64 + lane) * 8);
                #pragma unroll
                for (int m = 0; m < 4; ++m) {
                    int row = m * 16 + c;
                    bf16x8 a = *(const bf16x8*)&xb[row * 64 + ((kb * 32 + g * 8) ^ ((row & 7) << 3))];
                    ar[m]  = __builtin_amdgcn_mfma_f32_16x16x32_bf16(a, br, ar[m], 0, 0, 0);
                    az[m]  = __builtin_amdgcn_mfma_f32_16x16x32_bf16(a, bz, az[m], 0, 0, 0);
                    ain[m] = __builtin_amdgcn_mfma_f32_16x16x32_bf16(a, bn, ain[m], 0, 0, 0);
                }
            }
            // ---- gh = h . W_hh^T  (K=512); h==0 at l==0 ----
            if (l > 0) {
                #pragma unroll 4
                for (int kb = 0; kb < 16; ++kb) {
                    bf16x8 br = *(const bf16x8*)(wbh + (((size_t)((jt     ) * 16 + kb)) * 64 + lane) * 8);
                    bf16x8 bz = *(const bf16x8*)(wbh + (((size_t)((32 + jt) * 16 + kb)) * 64 + lane) * 8);
                    bf16x8 bn = *(const bf16x8*)(wbh + (((size_t)((64 + jt) * 16 + kb)) * 64 + lane) * 8);
                    #pragma unroll
                    for (int m = 0; m < 4; ++m) {
                        int row = m * 16 + c;
                        bf16x8 a = *(const bf16x8*)&hb[rbuf][row * 512 + ((kb * 32 + g * 8) ^ ((row & 7) << 3))];
                        ar[m]  = __builtin_amdgcn_mfma_f32_16x16x32_bf16(a, br, ar[m], 0, 0, 0);
                        az[m]  = __builtin_amdgcn_mfma_f32_16x16x32_bf16(a, bz, az[m], 0, 0, 0);
                        ahn[m] = __builtin_amdgcn_mfma_f32_16x16x32_bf16(a, bn, ahn[m], 0, 0, 0);
                    }
                }
            }
            // ---- gate combine (fp32) ----
            const int j = j0 + c;
            const float brr = b_ih[j] + b_hh[j];
            const float bzz = b_ih[512 + j] + b_hh[512 + j];
            const float bin = b_ih[1024 + j];
            const float bhn = b_hh[1024 + j];
            #pragma unroll
            for (int m = 0; m < 4; ++m) {
                #pragma unroll
                for (int q = 0; q < 4; ++q) {
                    int row = m * 16 + g * 4 + q;
                    int hidx = row * 512 + (j ^ ((row & 7) << 3));
                    float hold = (l > 0) ? bf2f(hb[rbuf][hidx]) : 0.f;
                    float r  = 1.f / (1.f + __expf(-(ar[m][q] + brr)));
                    float z  = 1.f / (1.f + __expf(-(az[m][q] + bzz)));
                    float pn = ain[m][q] + bin + r * (ahn[m][q] + bhn);
                    float ex = __expf(-2.f * pn);
                    float n  = (1.f - ex) / (1.f + ex);         // tanh
                    float hnew = (1.f - z) * n + z * hold;
                    if (l < 3) {
                        hb[wbuf][hidx] = f2bf(hnew);
                    } else {
                        int e = e0 + row;
                        if (e < E) eft[(size_t)e * 512 + j] = hnew;
                    }
                }
            }
        }
        __syncthreads();   // all reads of hb[rbuf]/xb done before next step
    }
}

// ---------------------------------------------------------------------------
__global__ __launch_bounds__(256) void attn_kernel(
    const float* __restrict__ eft, const float* __restrict__ attn,
    const int* __restrict__ dst, float* __restrict__ aexp,
    float* __restrict__ denom, int E)
{
    int gidx = blockIdx.x * 256 + threadIdx.x;
    if (gidx >= E * 8) return;
    int e = gidx >> 3, h = gidx & 7;
    const float* fp = &eft[(size_t)e * 512 + (h << 6)];
    const float* ap = &attn[h << 6];
    float a = 0.f;
    #pragma unroll
    for (int k = 0; k < 16; ++k) {
        float4 f = *(const float4*)(fp + (k << 2));
        float4 wv = *(const float4*)(ap + (k << 2));
        a += f.x * wv.x + f.y * wv.y + f.z * wv.z + f.w * wv.w;
    }
    a = (a > 0.f) ? a : 0.001f * a;   // leaky relu
    float ae = __expf(a);             // no max-sub: logits O(1), ratio identical
    aexp[gidx] = ae;
    atomicAdd(&denom[(size_t)dst[e] * 8 + h], ae);
}

__global__ __launch_bounds__(256) void scatter_kernel(
    const float* __restrict__ eft, const float* __restrict__ aexp,
    const float* __restrict__ denom, const int* __restrict__ dst,
    float* __restrict__ out, long long total)
{
    long long gi = (long long)blockIdx.x * 256 + threadIdx.x;
    if (gi >= total) return;
    int e = (int)(gi >> 9);
    int j = (int)(gi & 511);
    int h = j >> 6;
    int n = dst[e];
    float wv = aexp[(size_t)e * 8 + h] / fmaxf(denom[(size_t)n * 8 + h], 1e-12f);
    atomicAdd(&out[(size_t)n * 512 + j], eft[gi] * wv);
}

// ---------------------------------------------------------------------------
extern "C" void kernel_launch(void* const* d_in, const int* in_sizes, int n_in,
                              void* d_out, int out_size, void* d_ws, size_t ws_size,
                              hipStream_t stream)
{
    const float* feat = (const float*)d_in[0];
    const int*   emi  = (const int*)d_in[1];
    const int*   dst  = (const int*)d_in[2];
    const float* w_ih = (const float*)d_in[4];
    const float* w_hh = (const float*)d_in[5];
    const float* b_ih = (const float*)d_in[6];
    const float* b_hh = (const float*)d_in[7];
    const float* attn = (const float*)d_in[8];

    const int E = in_sizes[1] / 4;
    const int N = out_size / 512;
    const int nfeat8 = in_sizes[0] / 8;

    float* eft = (float*)d_ws;                                   // E*512 f32
    unsigned short* featb = (unsigned short*)(eft + (size_t)E * 512);
    unsigned short* wbi   = featb + (size_t)(in_sizes[0]);       // nfeat*64 u16
    unsigned short* wbh   = wbi + (size_t)96 * 2 * 64 * 8;
    // post-GRU aliases (featb/wbi/wbh dead after gru):
    float* aexp  = (float*)featb;            // E*8 f32
    float* denom = aexp + (size_t)E * 8;     // N*8 f32
    float* out   = (float*)d_out;

    int conv_total = nfeat8 + 98304 + 12288;
    conv_kernel<<<(conv_total + 255) / 256, 256, 0, stream>>>(
        feat, w_ih, w_hh, featb, wbi, wbh, nfeat8);

    gru_mfma_kernel<<<(E + EB - 1) / EB, 256, 0, stream>>>(
        featb, emi, wbi, wbh, b_ih, b_hh, eft, E);

    // denom aliases wbh tail -> must zero AFTER gru consumed weights
    (void)hipMemsetAsync(denom, 0, (size_t)N * 8 * sizeof(float), stream);
    (void)hipMemsetAsync(d_out, 0, (size_t)out_size * sizeof(float), stream);

    attn_kernel<<<(E * 8 + 255) / 256, 256, 0, stream>>>(eft, attn, dst, aexp, denom, E);

    long long total = (long long)E * 512;
    scatter_kernel<<<(int)((total + 255) / 256), 256, 0, stream>>>(
        eft, aexp, denom, dst, out, total);
}

// Round 4
// 1783.521 us; speedup vs baseline: 19.1418x; 1.1068x over previous
//
#include <hip/hip_runtime.h>
#include <cstdint>

typedef __attribute__((ext_vector_type(8))) short          bf16x8;
typedef __attribute__((ext_vector_type(8))) unsigned short u16x8;
typedef __attribute__((ext_vector_type(4))) float          f32x4;

__device__ __forceinline__ unsigned short f2bf(float x) {
    union { float f; unsigned u; } v; v.f = x;
    unsigned r = v.u + 0x7FFF + ((v.u >> 16) & 1);   // RNE
    return (unsigned short)(r >> 16);
}
__device__ __forceinline__ float bf2f(unsigned short b) {
    union { float f; unsigned u; } v; v.u = ((unsigned)b) << 16;
    return v.f;
}

#define EB 64   // edges per block

// ---------------------------------------------------------------------------
// One-time converts: feat -> bf16 row-major; w_ih/w_hh -> bf16 in MFMA
// B-fragment-linear order: wb[(jt_glob*KB + kb)*64 + lane][i] holds
// W[jt_glob*16 + (lane&15)][kb*32 + (lane>>4)*8 + i].
// ---------------------------------------------------------------------------
__global__ __launch_bounds__(256) void conv_kernel(
    const float* __restrict__ feat, const float* __restrict__ w_ih,
    const float* __restrict__ w_hh,
    unsigned short* __restrict__ featb, unsigned short* __restrict__ wbi,
    unsigned short* __restrict__ wbh, int nfeat8)
{
    int t = blockIdx.x * 256 + threadIdx.x;
    if (t < nfeat8) {
        u16x8 o;
        #pragma unroll
        for (int i = 0; i < 8; ++i) o[i] = f2bf(feat[(size_t)t * 8 + i]);
        *(u16x8*)&featb[(size_t)t * 8] = o;
    } else if (t < nfeat8 + 98304) {        // w_hh: 96 jt x 16 kb x 64 lanes
        int tt = t - nfeat8;
        int lane = tt & 63, q = tt >> 6;
        int jt = q >> 4, kb = q & 15;
        int j = jt * 16 + (lane & 15);
        int k0 = kb * 32 + (lane >> 4) * 8;
        u16x8 o;
        #pragma unroll
        for (int i = 0; i < 8; ++i) o[i] = f2bf(w_hh[(size_t)j * 512 + k0 + i]);
        *(u16x8*)&wbh[(size_t)tt * 8] = o;
    } else if (t < nfeat8 + 98304 + 12288) { // w_ih: 96 jt x 2 kb x 64 lanes
        int uu = t - nfeat8 - 98304;
        int lane = uu & 63, q = uu >> 6;
        int jt = q >> 1, kb = q & 1;
        int j = jt * 16 + (lane & 15);
        int k0 = kb * 32 + (lane >> 4) * 8;
        u16x8 o;
        #pragma unroll
        for (int i = 0; i < 8; ++i) o[i] = f2bf(w_ih[(size_t)j * 64 + k0 + i]);
        *(u16x8*)&wbi[(size_t)uu * 8] = o;
    }
}

// ---------------------------------------------------------------------------
// GRU via mfma_f32_16x16x32_bf16.  Block = 64 edges, 512 threads (8 waves).
// Wave w owns j in [w*64, w*64+64) for ALL 64 edges.
// h state: SINGLE 64 KB LDS buffer (bf16, XOR-swizzled).  Between steps,
// h_new round-trips through global memory: each edge's h (bf16, 1 KB) lives
// in the first 1 KB of that edge's eft row (eft rows are 2 KB; block-private;
// the fp32 eft result overwrites it only at l==3, after the last restage).
// Cross-wave visibility: plain stores drain at __syncthreads (vmcnt 0);
// restage reads use volatile (sc0) loads -> L2, bypassing stale L1.
// ---------------------------------------------------------------------------
__global__ __launch_bounds__(512, 4) void gru_mfma_kernel(
    const unsigned short* __restrict__ featb,
    const int* __restrict__ emi,
    const unsigned short* __restrict__ wbi,
    const unsigned short* __restrict__ wbh,
    const float* __restrict__ b_ih,
    const float* __restrict__ b_hh,
    float* __restrict__ eft,
    int E)
{
    __shared__ unsigned short hb[64 * 512];  // 64 KB, single buffer
    __shared__ unsigned short xb[64 * 64];   // 8 KB

    const int tid  = threadIdx.x;
    const int lane = tid & 63;
    const int w    = tid >> 6;       // 0..7
    const int g    = lane >> 4;
    const int c    = lane & 15;
    const int e0   = blockIdx.x * EB;
    const f32x4 fzero = {0.f, 0.f, 0.f, 0.f};

    for (int l = 0; l < 4; ++l) {
        // ---- stage x: 64 rows x 128 B, 512 threads x 16 B ----
        {
            int r = tid >> 3, p = tid & 7;
            int nidx = (e0 + r < E) ? emi[(e0 + r) * 4 + l] : 0;
            u16x8 v = *(const u16x8*)(featb + (size_t)nidx * 64 + p * 8);
            *(u16x8*)&xb[r * 64 + ((p * 8) ^ ((r & 7) << 3))] = v;
        }
        // ---- restage h from global (l>0): 4096 16B-chunks / 512 thr = 8 ----
        if (l > 0) {
            #pragma unroll
            for (int it = 0; it < 8; ++it) {
                int q = it * 512 + tid;
                int row = q >> 6, col8 = q & 63;
                const volatile unsigned* hsrc =
                    (const volatile unsigned*)((const char*)eft + (size_t)(e0 + row) * 2048) + (col8 << 2);
                unsigned u0 = hsrc[0], u1 = hsrc[1], u2 = hsrc[2], u3 = hsrc[3];
                uint4 v = {u0, u1, u2, u3};
                *(uint4*)&hb[row * 512 + (((col8 << 3)) ^ ((row & 7) << 3))] = v;
            }
        }
        __syncthreads();

        for (int cc = 0; cc < 4; ++cc) {
            const int j0 = (w << 6) + (cc << 4);
            const int jt = j0 >> 4;           // 0..31 within a gate block
            f32x4 ar[4], az[4], ain[4], ahn[4];
            #pragma unroll
            for (int m = 0; m < 4; ++m) { ar[m] = fzero; az[m] = fzero; ain[m] = fzero; ahn[m] = fzero; }

            // ---- gi = x . W_ih^T  (K=64) ----
            #pragma unroll
            for (int kb = 0; kb < 2; ++kb) {
                bf16x8 br = *(const bf16x8*)(wbi + (((size_t)((jt     ) * 2 + kb)) * 64 + lane) * 8);
                bf16x8 bz = *(const bf16x8*)(wbi + (((size_t)((32 + jt) * 2 + kb)) * 64 + lane) * 8);
                bf16x8 bn = *(const bf16x8*)(wbi + (((size_t)((64 + jt) * 2 + kb)) * 64 + lane) * 8);
                #pragma unroll
                for (int m = 0; m < 4; ++m) {
                    int row = m * 16 + c;
                    bf16x8 a = *(const bf16x8*)&xb[row * 64 + ((kb * 32 + g * 8) ^ ((row & 7) << 3))];
                    ar[m]  = __builtin_amdgcn_mfma_f32_16x16x32_bf16(a, br, ar[m], 0, 0, 0);
                    az[m]  = __builtin_amdgcn_mfma_f32_16x16x32_bf16(a, bz, az[m], 0, 0, 0);
                    ain[m] = __builtin_amdgcn_mfma_f32_16x16x32_bf16(a, bn, ain[m], 0, 0, 0);
                }
            }
            // ---- gh = h . W_hh^T  (K=512); h==0 at l==0 ----
            if (l > 0) {
                #pragma unroll 2
                for (int kb = 0; kb < 16; ++kb) {
                    bf16x8 br = *(const bf16x8*)(wbh + (((size_t)((jt     ) * 16 + kb)) * 64 + lane) * 8);
                    bf16x8 bz = *(const bf16x8*)(wbh + (((size_t)((32 + jt) * 16 + kb)) * 64 + lane) * 8);
                    bf16x8 bn = *(const bf16x8*)(wbh + (((size_t)((64 + jt) * 16 + kb)) * 64 + lane) * 8);
                    #pragma unroll
                    for (int m = 0; m < 4; ++m) {
                        int row = m * 16 + c;
                        bf16x8 a = *(const bf16x8*)&hb[row * 512 + ((kb * 32 + g * 8) ^ ((row & 7) << 3))];
                        ar[m]  = __builtin_amdgcn_mfma_f32_16x16x32_bf16(a, br, ar[m], 0, 0, 0);
                        az[m]  = __builtin_amdgcn_mfma_f32_16x16x32_bf16(a, bz, az[m], 0, 0, 0);
                        ahn[m] = __builtin_amdgcn_mfma_f32_16x16x32_bf16(a, bn, ahn[m], 0, 0, 0);
                    }
                }
            }
            // ---- gate combine (fp32) ----
            const int j = j0 + c;
            const float brr = b_ih[j] + b_hh[j];
            const float bzz = b_ih[512 + j] + b_hh[512 + j];
            const float bin = b_ih[1024 + j];
            const float bhn = b_hh[1024 + j];
            #pragma unroll
            for (int m = 0; m < 4; ++m) {
                #pragma unroll
                for (int q = 0; q < 4; ++q) {
                    int row = m * 16 + g * 4 + q;
                    float hold = (l > 0) ? bf2f(hb[row * 512 + (j ^ ((row & 7) << 3))]) : 0.f;
                    float r  = 1.f / (1.f + __expf(-(ar[m][q] + brr)));
                    float z  = 1.f / (1.f + __expf(-(az[m][q] + bzz)));
                    float pn = ain[m][q] + bin + r * (ahn[m][q] + bhn);
                    float ex = __expf(-2.f * pn);
                    float n  = (1.f - ex) / (1.f + ex);         // tanh
                    float hnew = (1.f - z) * n + z * hold;
                    int e = e0 + row;
                    if (e < E) {
                        if (l < 3) {
                            unsigned short* hrow = (unsigned short*)((char*)eft + (size_t)e * 2048);
                            hrow[j] = f2bf(hnew);
                        } else {
                            eft[(size_t)e * 512 + j] = hnew;
                        }
                    }
                }
            }
        }
        __syncthreads();   // h_new stores drained (vmcnt 0) before restage reads
    }
}

// ---------------------------------------------------------------------------
__global__ __launch_bounds__(256) void attn_kernel(
    const float* __restrict__ eft, const float* __restrict__ attn,
    const int* __restrict__ dst, float* __restrict__ aexp,
    float* __restrict__ denom, int E)
{
    int gidx = blockIdx.x * 256 + threadIdx.x;
    if (gidx >= E * 8) return;
    int e = gidx >> 3, h = gidx & 7;
    const float* fp = &eft[(size_t)e * 512 + (h << 6)];
    const float* ap = &attn[h << 6];
    float a = 0.f;
    #pragma unroll
    for (int k = 0; k < 16; ++k) {
        float4 f = *(const float4*)(fp + (k << 2));
        float4 wv = *(const float4*)(ap + (k << 2));
        a += f.x * wv.x + f.y * wv.y + f.z * wv.z + f.w * wv.w;
    }
    a = (a > 0.f) ? a : 0.001f * a;   // leaky relu
    float ae = __expf(a);             // no max-sub: logits O(1), ratio identical
    aexp[gidx] = ae;
    atomicAdd(&denom[(size_t)dst[e] * 8 + h], ae);
}

__global__ __launch_bounds__(256) void scatter_kernel(
    const float* __restrict__ eft, const float* __restrict__ aexp,
    const float* __restrict__ denom, const int* __restrict__ dst,
    float* __restrict__ out, long long total)
{
    long long gi = (long long)blockIdx.x * 256 + threadIdx.x;
    if (gi >= total) return;
    int e = (int)(gi >> 9);
    int j = (int)(gi & 511);
    int h = j >> 6;
    int n = dst[e];
    float wv = aexp[(size_t)e * 8 + h] / fmaxf(denom[(size_t)n * 8 + h], 1e-12f);
    atomicAdd(&out[(size_t)n * 512 + j], eft[gi] * wv);
}

// ---------------------------------------------------------------------------
extern "C" void kernel_launch(void* const* d_in, const int* in_sizes, int n_in,
                              void* d_out, int out_size, void* d_ws, size_t ws_size,
                              hipStream_t stream)
{
    const float* feat = (const float*)d_in[0];
    const int*   emi  = (const int*)d_in[1];
    const int*   dst  = (const int*)d_in[2];
    const float* w_ih = (const float*)d_in[4];
    const float* w_hh = (const float*)d_in[5];
    const float* b_ih = (const float*)d_in[6];
    const float* b_hh = (const float*)d_in[7];
    const float* attn = (const float*)d_in[8];

    const int E = in_sizes[1] / 4;
    const int N = out_size / 512;
    const int nfeat8 = in_sizes[0] / 8;

    float* eft = (float*)d_ws;                                   // E*512 f32 (h scratch lives in row heads)
    unsigned short* featb = (unsigned short*)(eft + (size_t)E * 512);
    unsigned short* wbi   = featb + (size_t)(in_sizes[0]);       // nfeat*64 u16
    unsigned short* wbh   = wbi + (size_t)96 * 2 * 64 * 8;
    // post-GRU aliases (featb/wbi/wbh dead after gru):
    float* aexp  = (float*)featb;            // E*8 f32
    float* denom = aexp + (size_t)E * 8;     // N*8 f32
    float* out   = (float*)d_out;

    int conv_total = nfeat8 + 98304 + 12288;
    conv_kernel<<<(conv_total + 255) / 256, 256, 0, stream>>>(
        feat, w_ih, w_hh, featb, wbi, wbh, nfeat8);

    gru_mfma_kernel<<<(E + EB - 1) / EB, 512, 0, stream>>>(
        featb, emi, wbi, wbh, b_ih, b_hh, eft, E);

    // denom aliases workspace tail -> zero AFTER gru consumed weights
    (void)hipMemsetAsync(denom, 0, (size_t)N * 8 * sizeof(float), stream);
    (void)hipMemsetAsync(d_out, 0, (size_t)out_size * sizeof(float), stream);

    attn_kernel<<<(E * 8 + 255) / 256, 256, 0, stream>>>(eft, attn, dst, aexp, denom, E);

    long long total = (long long)E * 512;
    scatter_kernel<<<(int)((total + 255) / 256), 256, 0, stream>>>(
        eft, aexp, denom, dst, out, total);
}